// Round 1
// baseline (621.367 us; speedup 1.0000x reference)
//
#include <hip/hip_runtime.h>

// NeuralODE: z0 = enc(y0); 100 x Tsit5 steps of f = W3 tanh(W2 tanh(W1 y + b1) + b2) + b3;
// outputs ys = dec(z_t), zs = z_t.  One wave (64 thr) per 16 batch elements, grid 256.
//
// GEMM orientation: D[row, elem] = W[row, k] * Act[k, elem] with mfma_f32_16x16x32_f16.
// Lane l = (e = l&15, q = l>>4). C/D: lane holds rows p = 16t+4q+r (t = M-tile, r = reg).
// Consumer weight k-columns are pre-shuffled by kappa so that the producer's C/D registers
// ARE the consumer's lane-local B-fragment: B slot j of K-tile kt == state[8*kt + j],
// where state[4t+r] = row p = 16t+4q+r.  kappa64(p)=32(t>>1)+8q+4(t&1)+r, kappa32(p)=8q+4t+r.
// 3-term f16 hi/lo split (Whi*Bhi + Wlo*Bhi + Whi*Blo) keeps per-product error ~2^-22.

typedef __attribute__((ext_vector_type(8))) _Float16 half8;
typedef __attribute__((ext_vector_type(4))) float f32x4;

static constexpr int TN = 101;
static constexpr int BN = 4096;

#define MFMA(a, b, c) __builtin_amdgcn_mfma_f32_16x16x32_f16((a), (b), (c), 0, 0, 0)

__device__ __forceinline__ float tanh_fast(float x) {
  // tanh(x) = 1 - 2/(1+e^{2x}); exact at +/-inf via exp2 overflow/underflow.
  float e = __builtin_amdgcn_exp2f(x * 2.8853900817779268f);  // 2/ln2
  float r = __builtin_amdgcn_rcpf(e + 1.0f);
  return __builtin_fmaf(-2.0f, r, 1.0f);
}

__device__ __forceinline__ void split8(const float* v, half8& hi, half8& lo) {
#pragma unroll
  for (int j = 0; j < 8; ++j) {
    _Float16 h = (_Float16)v[j];
    hi[j] = h;
    lo[j] = (_Float16)(v[j] - (float)h);
  }
}

// A-fragment for a weight whose k-columns are consumed kappa-shuffled:
// slot j of lane q, K-tile kt  <-  W[row][kt*32 + 16*(j>>2) + 4*q + (j&3)]
__device__ __forceinline__ void load_wfrag(const float* __restrict__ W, int C, int row, int q,
                                           int kt, half8& hi, half8& lo) {
  const float* p = W + row * C + kt * 32 + 4 * q;
  float v[8] __attribute__((aligned(16)));
  *(f32x4*)(v) = *(const f32x4*)(p);
  *(f32x4*)(v + 4) = *(const f32x4*)(p + 16);
  split8(v, hi, lo);
}

__global__ __launch_bounds__(64, 1) void node_kernel(
    const float* __restrict__ ts, const float* __restrict__ y0,
    const float* __restrict__ encW, const float* __restrict__ encb,
    const float* __restrict__ W1, const float* __restrict__ b1,
    const float* __restrict__ W2, const float* __restrict__ b2,
    const float* __restrict__ W3, const float* __restrict__ b3,
    const float* __restrict__ decW, const float* __restrict__ decb,
    float* __restrict__ out) {
  const int l = threadIdx.x;
  const int lm = l & 15;
  const int q = l >> 4;
  const int eg = blockIdx.x * 16 + lm;

  __shared__ half8 s_dec[4][2][64];   // decoder A-frags (f16, hi only), SoA: conflict-free
  __shared__ f32x4 s_decb[4][64];

  // ---- persistent MLP weight fragments (f16 hi+lo) ----
  half8 w1h[2][2], w1l[2][2], w2h[2], w2l[2], w3h[4], w3l[4];
#pragma unroll
  for (int mt = 0; mt < 2; ++mt) {
#pragma unroll
    for (int kt = 0; kt < 2; ++kt)
      load_wfrag(W1, 64, 16 * mt + lm, q, kt, w1h[mt][kt], w1l[mt][kt]);
    load_wfrag(W2, 32, 16 * mt + lm, q, 0, w2h[mt], w2l[mt]);
  }
#pragma unroll
  for (int mt = 0; mt < 4; ++mt) load_wfrag(W3, 32, 16 * mt + lm, q, 0, w3h[mt], w3l[mt]);

  f32x4 b1f[2], b2f[2], b3f[4];
#pragma unroll
  for (int mt = 0; mt < 2; ++mt) {
    b1f[mt] = *(const f32x4*)(b1 + 16 * mt + 4 * q);
    b2f[mt] = *(const f32x4*)(b2 + 16 * mt + 4 * q);
  }
#pragma unroll
  for (int mt = 0; mt < 4; ++mt) b3f[mt] = *(const f32x4*)(b3 + 16 * mt + 4 * q);

  // ---- decoder frags -> LDS (single f16: decoder error does not feed back) ----
#pragma unroll
  for (int mt = 0; mt < 4; ++mt) {
#pragma unroll
    for (int kt = 0; kt < 2; ++kt) {
      const float* p = decW + (16 * mt + lm) * 64 + kt * 32 + 4 * q;
      float v[8] __attribute__((aligned(16)));
      *(f32x4*)(v) = *(const f32x4*)(p);
      *(f32x4*)(v + 4) = *(const f32x4*)(p + 16);
      half8 h;
#pragma unroll
      for (int j = 0; j < 8; ++j) h[j] = (_Float16)v[j];
      s_dec[mt][kt][l] = h;
    }
    s_decb[mt][l] = *(const f32x4*)(decb + 16 * mt + 4 * q);
  }
  __syncthreads();

  float z[16];

  // ---- encoder: z0 = encW * y0^T + encb (enc cols in TRUE order; y0 frag = 8 consecutive) ----
  {
    const float* yp = y0 + (size_t)eg * 64;
    float v[16] __attribute__((aligned(16)));
    *(f32x4*)(v) = *(const f32x4*)(yp + 8 * q);
    *(f32x4*)(v + 4) = *(const f32x4*)(yp + 8 * q + 4);
    *(f32x4*)(v + 8) = *(const f32x4*)(yp + 32 + 8 * q);
    *(f32x4*)(v + 12) = *(const f32x4*)(yp + 32 + 8 * q + 4);
    half8 xh[2], xl[2];
    split8(v, xh[0], xl[0]);
    split8(v + 8, xh[1], xl[1]);
#pragma unroll
    for (int mt = 0; mt < 4; ++mt) {
      const float* p0 = encW + (16 * mt + lm) * 64 + 8 * q;
      float w[8] __attribute__((aligned(16)));
      half8 eh, el;
      f32x4 a = *(const f32x4*)(encb + 16 * mt + 4 * q);
      *(f32x4*)(w) = *(const f32x4*)(p0);
      *(f32x4*)(w + 4) = *(const f32x4*)(p0 + 4);
      split8(w, eh, el);
      a = MFMA(eh, xh[0], a);
      a = MFMA(el, xh[0], a);
      a = MFMA(eh, xl[0], a);
      *(f32x4*)(w) = *(const f32x4*)(p0 + 32);
      *(f32x4*)(w + 4) = *(const f32x4*)(p0 + 36);
      split8(w, eh, el);
      a = MFMA(eh, xh[1], a);
      a = MFMA(el, xh[1], a);
      a = MFMA(eh, xl[1], a);
#pragma unroll
      for (int r = 0; r < 4; ++r) z[4 * mt + r] = a[r];
    }
  }

  // ---- helpers ----
  auto evalf = [&](const float (&yv)[16], float (&kv)[16]) {
    half8 yh[2], yl[2];
    split8(yv, yh[0], yl[0]);
    split8(yv + 8, yh[1], yl[1]);
    float h1[8], h2[8];
#pragma unroll
    for (int mt = 0; mt < 2; ++mt) {
      f32x4 a = b1f[mt];
      a = MFMA(w1h[mt][0], yh[0], a);
      a = MFMA(w1l[mt][0], yh[0], a);
      a = MFMA(w1h[mt][0], yl[0], a);
      a = MFMA(w1h[mt][1], yh[1], a);
      a = MFMA(w1l[mt][1], yh[1], a);
      a = MFMA(w1h[mt][1], yl[1], a);
#pragma unroll
      for (int r = 0; r < 4; ++r) h1[4 * mt + r] = tanh_fast(a[r]);
    }
    half8 hh, hl;
    split8(h1, hh, hl);
#pragma unroll
    for (int mt = 0; mt < 2; ++mt) {
      f32x4 a = b2f[mt];
      a = MFMA(w2h[mt], hh, a);
      a = MFMA(w2l[mt], hh, a);
      a = MFMA(w2h[mt], hl, a);
#pragma unroll
      for (int r = 0; r < 4; ++r) h2[4 * mt + r] = tanh_fast(a[r]);
    }
    split8(h2, hh, hl);
#pragma unroll
    for (int mt = 0; mt < 4; ++mt) {
      f32x4 a = b3f[mt];
      a = MFMA(w3h[mt], hh, a);
      a = MFMA(w3l[mt], hh, a);
      a = MFMA(w3h[mt], hl, a);
#pragma unroll
      for (int r = 0; r < 4; ++r) kv[4 * mt + r] = a[r];
    }
  };

  auto store_z = [&](const float (&x)[16], int s) {
    float* zb = out + (size_t)BN * TN * 64 + ((size_t)eg * TN + s) * 64;
#pragma unroll
    for (int t = 0; t < 4; ++t) {
      f32x4 v = {x[4 * t], x[4 * t + 1], x[4 * t + 2], x[4 * t + 3]};
      *(f32x4*)(zb + 16 * t + 4 * q) = v;  // row p = 16t+4q+r, true dim order
    }
  };

  auto dec_store = [&](const float (&x)[16], int s) {
    half8 xh[2];
#pragma unroll
    for (int j = 0; j < 8; ++j) {
      xh[0][j] = (_Float16)x[j];
      xh[1][j] = (_Float16)x[8 + j];
    }
    float* yb = out + ((size_t)eg * TN + s) * 64;
#pragma unroll
    for (int mt = 0; mt < 4; ++mt) {
      f32x4 a = s_decb[mt][l];
      a = MFMA(s_dec[mt][0][l], xh[0], a);
      a = MFMA(s_dec[mt][1][l], xh[1], a);
      *(f32x4*)(yb + 16 * mt + 4 * q) = a;
    }
  };

  store_z(z, 0);
  dec_store(z, 0);

  const float dt = (ts[TN - 1] - ts[0]) / (float)(TN - 1);
  const float A21 = 0.161f;
  const float A31 = -0.008480655492356989f, A32 = 0.335480655492357f;
  const float A41 = 2.8971530571054935f, A42 = -6.359448489975075f, A43 = 4.3622954328695815f;
  const float A51 = 5.325864828439257f, A52 = -11.748883564062828f, A53 = 7.4955393428898365f,
              A54 = -0.09249506636175525f;
  const float A61 = 5.86145544294642f, A62 = -12.92096931784711f, A63 = 8.159367898576159f,
              A64 = -0.071584973281401f, A65 = -0.028269050394068383f;
  const float B1 = 0.09646076681806523f, B2 = 0.01f, B3 = 0.4798896504144996f,
              B4 = 1.379008574103742f, B5 = -3.290069515436081f, B6 = 2.324710524099774f;

#pragma nounroll
  for (int s = 1; s < TN; ++s) {
    float k1[16], k2[16], k3[16], k4[16], k5[16], k6[16], y[16];
    evalf(z, k1);
#pragma unroll
    for (int i = 0; i < 16; ++i) y[i] = __builtin_fmaf(dt, A21 * k1[i], z[i]);
    evalf(y, k2);
#pragma unroll
    for (int i = 0; i < 16; ++i)
      y[i] = __builtin_fmaf(dt, __builtin_fmaf(A32, k2[i], A31 * k1[i]), z[i]);
    evalf(y, k3);
#pragma unroll
    for (int i = 0; i < 16; ++i)
      y[i] = __builtin_fmaf(
          dt, __builtin_fmaf(A43, k3[i], __builtin_fmaf(A42, k2[i], A41 * k1[i])), z[i]);
    evalf(y, k4);
#pragma unroll
    for (int i = 0; i < 16; ++i)
      y[i] = __builtin_fmaf(
          dt,
          __builtin_fmaf(A54, k4[i],
                         __builtin_fmaf(A53, k3[i], __builtin_fmaf(A52, k2[i], A51 * k1[i]))),
          z[i]);
    evalf(y, k5);
#pragma unroll
    for (int i = 0; i < 16; ++i)
      y[i] = __builtin_fmaf(
          dt,
          __builtin_fmaf(
              A65, k5[i],
              __builtin_fmaf(A64, k4[i],
                             __builtin_fmaf(A63, k3[i],
                                            __builtin_fmaf(A62, k2[i], A61 * k1[i])))),
          z[i]);
    evalf(y, k6);
#pragma unroll
    for (int i = 0; i < 16; ++i)
      z[i] = __builtin_fmaf(
          dt,
          __builtin_fmaf(
              B6, k6[i],
              __builtin_fmaf(
                  B5, k5[i],
                  __builtin_fmaf(B4, k4[i],
                                 __builtin_fmaf(B3, k3[i],
                                                __builtin_fmaf(B2, k2[i], B1 * k1[i]))))),
          z[i]);
    store_z(z, s);
    dec_store(z, s);
  }
}

extern "C" void kernel_launch(void* const* d_in, const int* in_sizes, int n_in,
                              void* d_out, int out_size, void* d_ws, size_t ws_size,
                              hipStream_t stream) {
  const float* ts = (const float*)d_in[0];
  const float* y0 = (const float*)d_in[1];
  const float* encW = (const float*)d_in[2];
  const float* encb = (const float*)d_in[3];
  const float* W1 = (const float*)d_in[4];
  const float* b1 = (const float*)d_in[5];
  const float* W2 = (const float*)d_in[6];
  const float* b2 = (const float*)d_in[7];
  const float* W3 = (const float*)d_in[8];
  const float* b3 = (const float*)d_in[9];
  const float* decW = (const float*)d_in[10];
  const float* decb = (const float*)d_in[11];
  node_kernel<<<BN / 16, 64, 0, stream>>>(ts, y0, encW, encb, W1, b1, W2, b2, W3, b3, decW, decb,
                                          (float*)d_out);
}